// Round 1
// baseline (2185.255 us; speedup 1.0000x reference)
//
#include <hip/hip_runtime.h>

// ---------------------------------------------------------------------------
// Problem: B=256, C=2 (only ch0 used), T=25, D=4096, H=512, H1=128, NC=2
// zx = xc @ kernel + bias          (6400 x 2048, K=4096)  -- bf16 MFMA
// LSTM scan over T=25:  z = zx[:,t,:] + h @ rec_kernel ; gates ; c,h update
// head: softmax(leaky_relu(h@w1+b1) @ w2 + b2)
// ---------------------------------------------------------------------------

typedef __bf16 bf16x8 __attribute__((ext_vector_type(8)));
typedef float  f32x4  __attribute__((ext_vector_type(4)));

#define MFMA16(a, b, c) __builtin_amdgcn_mfma_f32_16x16x32_bf16((a), (b), (c), 0, 0, 0)

__device__ __forceinline__ float sigmf(float x) {
  return 1.0f / (1.0f + __expf(-x));
}
__device__ __forceinline__ float tanhf_(float x) {
  float a = fabsf(x);
  float e = __expf(-2.0f * a);
  float r = (1.0f - e) / (1.0f + e);
  return copysignf(r, x);
}

// ---------------------------------------------------------------------------
// rec_kernel (512 x 2048) fp32 -> recT (2048 x 512) bf16   (write-coalesced)
// ---------------------------------------------------------------------------
__global__ __launch_bounds__(256) void conv_recT(const float* __restrict__ rec,
                                                 __bf16* __restrict__ recT) {
  int o = blockIdx.x * 256 + threadIdx.x;   // 0 .. 2048*512-1
  int g = o >> 9;        // 0..2047
  int k = o & 511;       // 0..511
  recT[o] = (__bf16)rec[(long)k * 2048 + g];
}

// ---------------------------------------------------------------------------
// GEMM1: zx[m][n] = sum_k xc[m][k]*kernel[k][n] + bias[n]
//   m = b*25+t (6400), n (2048), k (4096).  xc row base = b*204800 + t*4096.
// 128x128 tile, BK=64, 4 waves (2x2), each wave 64x64 = 4x4 16x16 frags.
// LDS padded stride 72 (2-way bank alias only -> free).
// ---------------------------------------------------------------------------
#define LDSP 72

__global__ __launch_bounds__(256) void gemm_xk(const float* __restrict__ x,
                                               const float* __restrict__ wk,
                                               const float* __restrict__ bias,
                                               float* __restrict__ zx) {
  __shared__ __bf16 As[128 * LDSP];
  __shared__ __bf16 Bs[128 * LDSP];

  const int tid = threadIdx.x;
  const int m0 = blockIdx.y * 128;
  const int n0 = blockIdx.x * 128;

  // staging coords
  const int arow0 = tid >> 4;          // + 16*p  (A rows)
  const int kq    = (tid & 15) << 2;   // A k-offset (float4)
  const int krb   = tid >> 5;          // + 8*p   (B k rows)
  const int nq    = (tid & 31) << 2;   // B n-offset (float4)

  long abase[8];
#pragma unroll
  for (int p = 0; p < 8; ++p) {
    int m = m0 + arow0 + 16 * p;
    int b = m / 25;
    int t = m - b * 25;
    abase[p] = (long)b * 204800 + (long)t * 4096;
  }

  const int wid  = tid >> 6;
  const int lane = tid & 63;
  const int wr   = (wid >> 1) << 6;    // 0 or 64
  const int wc   = (wid & 1) << 6;     // 0 or 64
  const int lrow = lane & 15;
  const int lk8  = (lane >> 4) << 3;

  f32x4 acc[4][4];
#pragma unroll
  for (int i = 0; i < 4; ++i)
#pragma unroll
    for (int j = 0; j < 4; ++j) {
      f32x4 z = {0.f, 0.f, 0.f, 0.f};
      acc[i][j] = z;
    }

  for (int k0 = 0; k0 < 4096; k0 += 64) {
    __syncthreads();
    // stage A (128 x 64), fp32 -> bf16
#pragma unroll
    for (int p = 0; p < 8; ++p) {
      int row = arow0 + 16 * p;
      f32x4 v = *(const f32x4*)(x + abase[p] + k0 + kq);
      __bf16* dst = &As[row * LDSP + kq];
      dst[0] = (__bf16)v[0]; dst[1] = (__bf16)v[1];
      dst[2] = (__bf16)v[2]; dst[3] = (__bf16)v[3];
    }
    // stage B transposed: Bs[n][k] = wk[k0+k][n0+n]
#pragma unroll
    for (int p = 0; p < 8; ++p) {
      int kr = krb + 8 * p;
      f32x4 v = *(const f32x4*)(wk + (long)(k0 + kr) * 2048 + n0 + nq);
      Bs[(nq + 0) * LDSP + kr] = (__bf16)v[0];
      Bs[(nq + 1) * LDSP + kr] = (__bf16)v[1];
      Bs[(nq + 2) * LDSP + kr] = (__bf16)v[2];
      Bs[(nq + 3) * LDSP + kr] = (__bf16)v[3];
    }
    __syncthreads();

#pragma unroll
    for (int kk = 0; kk < 2; ++kk) {
      bf16x8 af[4], bf[4];
#pragma unroll
      for (int fr = 0; fr < 4; ++fr)
        af[fr] = *(const bf16x8*)&As[(wr + fr * 16 + lrow) * LDSP + kk * 32 + lk8];
#pragma unroll
      for (int fc = 0; fc < 4; ++fc)
        bf[fc] = *(const bf16x8*)&Bs[(wc + fc * 16 + lrow) * LDSP + kk * 32 + lk8];
#pragma unroll
      for (int fr = 0; fr < 4; ++fr)
#pragma unroll
        for (int fc = 0; fc < 4; ++fc)
          acc[fr][fc] = MFMA16(af[fr], bf[fc], acc[fr][fc]);
    }
  }

  // epilogue: D row=(l>>4)*4+r, col=l&15
  const int mlow = (lane >> 4) << 2;
#pragma unroll
  for (int fc = 0; fc < 4; ++fc) {
    int n = n0 + wc + fc * 16 + lrow;
    float bv = bias[n];
#pragma unroll
    for (int fr = 0; fr < 4; ++fr) {
      int mb = m0 + wr + fr * 16 + mlow;
#pragma unroll
      for (int r = 0; r < 4; ++r)
        zx[(long)(mb + r) * 2048 + n] = acc[fr][fc][r] + bv;
    }
  }
}

// ---------------------------------------------------------------------------
// LSTM step t: z = zx[:, t, :] + h_in @ rec ;  gates ; c,h update.
// Grid (8 j-tiles, 4 row-tiles) x 256 thr. Wave w owns rows r0+w*16 (16 rows),
// all 4 gates, 64 j's -> acc[gate][fc]. i/f/g/o for a (b,j) pair land in the
// same lane+reg, so the gate combine is register-local (no LDS).
// Operands read straight from L2-resident bf16 buffers (h 256KB, recT 2MB).
// ---------------------------------------------------------------------------
__global__ __launch_bounds__(256) void lstm_step(const float* __restrict__ zx,
                                                 const __bf16* __restrict__ recT,
                                                 const __bf16* __restrict__ hin,
                                                 __bf16* __restrict__ hout,
                                                 float* __restrict__ cbuf,
                                                 int t) {
  const int tid  = threadIdx.x;
  const int wid  = tid >> 6;
  const int lane = tid & 63;
  const int j0   = blockIdx.x << 6;              // 0..448
  const int r0   = (blockIdx.y << 6) + (wid << 4); // batch-row base of this wave
  const int lrow = lane & 15;
  const int lk8  = (lane >> 4) << 3;

  f32x4 acc[4][4];
#pragma unroll
  for (int i = 0; i < 4; ++i)
#pragma unroll
    for (int j = 0; j < 4; ++j) {
      f32x4 z = {0.f, 0.f, 0.f, 0.f};
      acc[i][j] = z;
    }

  for (int ks = 0; ks < 16; ++ks) {
    bf16x8 a = *(const bf16x8*)(hin + (r0 + lrow) * 512 + ks * 32 + lk8);
#pragma unroll
    for (int g = 0; g < 4; ++g) {
#pragma unroll
      for (int fc = 0; fc < 4; ++fc) {
        bf16x8 b = *(const bf16x8*)(recT +
            (long)(g * 512 + j0 + fc * 16 + lrow) * 512 + ks * 32 + lk8);
        acc[g][fc] = MFMA16(a, b, acc[g][fc]);
      }
    }
  }

  const int mlow = (lane >> 4) << 2;
#pragma unroll
  for (int fc = 0; fc < 4; ++fc) {
    int j = j0 + fc * 16 + lrow;
#pragma unroll
    for (int r = 0; r < 4; ++r) {
      int brow = r0 + mlow + r;
      long zb = (long)(brow * 25 + t) * 2048;
      float zi = acc[0][fc][r] + zx[zb + j];
      float zf = acc[1][fc][r] + zx[zb + 512 + j];
      float zg = acc[2][fc][r] + zx[zb + 1024 + j];
      float zo = acc[3][fc][r] + zx[zb + 1536 + j];
      float ig = sigmf(zi);
      float fg = sigmf(zf);
      float gg = tanhf_(zg);
      float og = sigmf(zo);
      int hidx = brow * 512 + j;
      float cn = fg * cbuf[hidx] + ig * gg;
      cbuf[hidx] = cn;
      hout[hidx] = (__bf16)(og * tanhf_(cn));
    }
  }
}

// ---------------------------------------------------------------------------
// head: y = leaky_relu(h@w1+b1); out = softmax(y@w2+b2). One block per batch.
// ---------------------------------------------------------------------------
__global__ __launch_bounds__(128) void head_kernel(const __bf16* __restrict__ h,
                                                   const float* __restrict__ w1,
                                                   const float* __restrict__ b1,
                                                   const float* __restrict__ w2,
                                                   const float* __restrict__ b2,
                                                   float* __restrict__ out) {
  const int b = blockIdx.x;
  const int j = threadIdx.x;
  float acc = b1[j];
#pragma unroll 8
  for (int k = 0; k < 512; ++k)
    acc += (float)h[b * 512 + k] * w1[k * 128 + j];
  float y = acc > 0.f ? acc : 0.2f * acc;

  __shared__ float s0[128], s1[128];
  s0[j] = y * w2[j * 2 + 0];
  s1[j] = y * w2[j * 2 + 1];
  __syncthreads();
#pragma unroll
  for (int s = 64; s > 0; s >>= 1) {
    if (j < s) { s0[j] += s0[j + s]; s1[j] += s1[j + s]; }
    __syncthreads();
  }
  if (j == 0) {
    float l0 = s0[0] + b2[0];
    float l1 = s1[0] + b2[1];
    float m  = fmaxf(l0, l1);
    float e0 = __expf(l0 - m);
    float e1 = __expf(l1 - m);
    float inv = 1.0f / (e0 + e1);
    out[b * 2 + 0] = e0 * inv;
    out[b * 2 + 1] = e1 * inv;
  }
}

// ---------------------------------------------------------------------------
extern "C" void kernel_launch(void* const* d_in, const int* in_sizes, int n_in,
                              void* d_out, int out_size, void* d_ws, size_t ws_size,
                              hipStream_t stream) {
  const float* x    = (const float*)d_in[0];  // (256,2,25,4096)
  const float* wk   = (const float*)d_in[1];  // (4096,2048)
  const float* rec  = (const float*)d_in[2];  // (512,2048)
  const float* bias = (const float*)d_in[3];  // (2048,)
  const float* w1   = (const float*)d_in[4];  // (512,128)
  const float* b1   = (const float*)d_in[5];  // (128,)
  const float* w2   = (const float*)d_in[6];  // (128,2)
  const float* b2   = (const float*)d_in[7];  // (2,)
  float* out = (float*)d_out;

  char* w = (char*)d_ws;
  float*  zx   = (float*)(w + 0);             // 6400*2048*4 = 52,428,800
  __bf16* recT = (__bf16*)(w + 52428800);     // 2048*512*2  =  2,097,152
  __bf16* hA   = (__bf16*)(w + 54525952);     // 256*512*2   =    262,144
  __bf16* hB   = (__bf16*)(w + 54788096);     // 256*512*2   =    262,144
  float*  cbuf = (float*)(w + 55050240);      // 256*512*4   =    524,288

  // zero initial LSTM state (ws is poisoned 0xAA before every call)
  hipMemsetAsync(hA, 0, 262144, stream);
  hipMemsetAsync(cbuf, 0, 524288, stream);

  conv_recT<<<4096, 256, 0, stream>>>(rec, recT);
  gemm_xk<<<dim3(16, 50), 256, 0, stream>>>(x, wk, bias, zx);

  for (int t = 0; t < 25; ++t) {
    const __bf16* hin = (t & 1) ? hB : hA;
    __bf16* hout      = (t & 1) ? hA : hB;
    lstm_step<<<dim3(8, 4), 256, 0, stream>>>(zx, recT, hin, hout, cbuf, t);
  }
  // t=24 (even) wrote hB
  head_kernel<<<256, 128, 0, stream>>>(hB, w1, b1, w2, b2, out);
}

// Round 2
// 755.774 us; speedup vs baseline: 2.8914x; 2.8914x over previous
//
#include <hip/hip_runtime.h>

// ---------------------------------------------------------------------------
// B=256, C=2 (ch0 only), T=25, D=4096, H=512, H1=128, NC=2
//  zx = xc @ kernel + bias        (6400 x 2048, K=4096)  bf16 MFMA (m97-style)
//  LSTM scan T=25 with fragment-ordered h/rec operands
//  head: softmax(leaky_relu(h@w1+b1) @ w2 + b2)
// ---------------------------------------------------------------------------

typedef __bf16 bf16x8 __attribute__((ext_vector_type(8)));
typedef float  f32x4  __attribute__((ext_vector_type(4)));

#define MFMA16(a, b, c) __builtin_amdgcn_mfma_f32_16x16x32_bf16((a), (b), (c), 0, 0, 0)

__device__ __forceinline__ float sigmf(float x) {
  return 1.0f / (1.0f + __expf(-x));
}
__device__ __forceinline__ float tanhf_(float x) {
  float a = fabsf(x);
  float e = __expf(-2.0f * a);
  float r = (1.0f - e) / (1.0f + e);
  return copysignf(r, x);
}

__device__ __forceinline__ void async16(__bf16* lds, const __bf16* g) {
  __builtin_amdgcn_global_load_lds(
      (const __attribute__((address_space(1))) unsigned int*)g,
      (__attribute__((address_space(3))) unsigned int*)lds, 16, 0, 0);
}

// ---------------------------------------------------------------------------
// x (256,2,25,4096) ch0 -> xb bf16 [6400][4096]   (fully coalesced both sides)
// ---------------------------------------------------------------------------
__global__ __launch_bounds__(256) void conv_xb(const float* __restrict__ x,
                                               __bf16* __restrict__ xb) {
  long o = ((long)blockIdx.x * 256 + threadIdx.x) * 8;
  int m = (int)(o >> 12);
  int k = (int)(o & 4095);
  int b = m / 25, t = m - b * 25;
  const float* src = x + (long)b * 204800 + (long)t * 4096 + k;
  f32x4 v0 = *(const f32x4*)src;
  f32x4 v1 = *(const f32x4*)(src + 4);
  bf16x8 r;
  r[0] = (__bf16)v0[0]; r[1] = (__bf16)v0[1];
  r[2] = (__bf16)v0[2]; r[3] = (__bf16)v0[3];
  r[4] = (__bf16)v1[0]; r[5] = (__bf16)v1[1];
  r[6] = (__bf16)v1[2]; r[7] = (__bf16)v1[3];
  *(bf16x8*)(xb + o) = r;
}

// ---------------------------------------------------------------------------
// kernel (4096,2048) fp32 -> wkT bf16 [2048][4096]  (LDS 64x64 tile transpose)
// ---------------------------------------------------------------------------
__global__ __launch_bounds__(256) void conv_wkT(const float* __restrict__ wk,
                                                __bf16* __restrict__ wkT) {
  __shared__ float tile[64][65];
  const int k0 = blockIdx.y * 64;
  const int n0 = blockIdx.x * 64;
  const int tx = threadIdx.x & 63;
  const int ty = threadIdx.x >> 6;
#pragma unroll
  for (int p = 0; p < 16; ++p) {
    int kr = ty + p * 4;
    tile[kr][tx] = wk[(long)(k0 + kr) * 2048 + n0 + tx];
  }
  __syncthreads();
#pragma unroll
  for (int p = 0; p < 16; ++p) {
    int nr = ty + p * 4;
    wkT[(long)(n0 + nr) * 4096 + k0 + tx] = (__bf16)tile[tx][nr];
  }
}

// ---------------------------------------------------------------------------
// rec_kernel (512,2048) fp32 -> recF bf16 in MFMA-B-fragment order:
//   recF[((g*32+jt)*16+ks)*512 + l*8 + i] = rec[ks*32+(l>>4)*8+i][g*512+jt*16+(l&15)]
// ---------------------------------------------------------------------------
__global__ __launch_bounds__(256) void conv_recF(const float* __restrict__ rec,
                                                 __bf16* __restrict__ recF) {
  int o = blockIdx.x * 256 + threadIdx.x;   // 0 .. 1048575
  int i  = o & 7;
  int l  = (o >> 3) & 63;
  int ks = (o >> 9) & 15;
  int jt = (o >> 13) & 31;
  int g  = o >> 18;
  int k = ks * 32 + ((l >> 4) << 3) + i;
  int n = g * 512 + jt * 16 + (l & 15);
  recF[o] = (__bf16)rec[(long)k * 2048 + n];
}

// ---------------------------------------------------------------------------
// GEMM (m97 structure): zx[m][n] = sum_k xb[m][k]*wkT[n][k] + bias[n]
// 128x128 tile, BK=64, 4 waves 2x2, global_load_lds width-16, linear LDS.
// ---------------------------------------------------------------------------
__global__ __launch_bounds__(256) void gemm_bf16(const __bf16* __restrict__ A,
                                                 const __bf16* __restrict__ Bt,
                                                 const float* __restrict__ bias,
                                                 float* __restrict__ zx) {
  __shared__ __bf16 As[128 * 64];
  __shared__ __bf16 Bs[128 * 64];
  const int tid  = threadIdx.x;
  const int wid  = tid >> 6;
  const int lane = tid & 63;
  const int m0 = blockIdx.y * 128;
  const int n0 = blockIdx.x * 128;

  // staging: wave w call q covers 8 rows starting at w*8 + q*32; lane l ->
  // row + (l>>3), k-offset (l&7)*8  (LDS dest = uniform base + l*16B)
  const int srow  = (wid << 3) + (lane >> 3);
  const int skoff = (lane & 7) << 3;

  const int wr   = (wid >> 1) << 6;
  const int wc   = (wid & 1) << 6;
  const int lrow = lane & 15;
  const int lk8  = (lane >> 4) << 3;

  f32x4 acc[4][4];
#pragma unroll
  for (int i = 0; i < 4; ++i)
#pragma unroll
    for (int j = 0; j < 4; ++j) {
      f32x4 z = {0.f, 0.f, 0.f, 0.f};
      acc[i][j] = z;
    }

  const __bf16* Ag = A  + (long)(m0 + srow) * 4096 + skoff;
  const __bf16* Bg = Bt + (long)(n0 + srow) * 4096 + skoff;
  __bf16* Al = &As[(wid << 3) * 64];
  __bf16* Bl = &Bs[(wid << 3) * 64];

  for (int k0 = 0; k0 < 4096; k0 += 64) {
    __syncthreads();
#pragma unroll
    for (int q = 0; q < 4; ++q) {
      async16(Al + q * (32 * 64), Ag + (long)(q * 32) * 4096 + k0);
      async16(Bl + q * (32 * 64), Bg + (long)(q * 32) * 4096 + k0);
    }
    __syncthreads();
#pragma unroll
    for (int kk = 0; kk < 2; ++kk) {
      bf16x8 af[4], bv[4];
#pragma unroll
      for (int fr = 0; fr < 4; ++fr)
        af[fr] = *(const bf16x8*)&As[(wr + fr * 16 + lrow) * 64 + (kk << 5) + lk8];
#pragma unroll
      for (int fc = 0; fc < 4; ++fc)
        bv[fc] = *(const bf16x8*)&Bs[(wc + fc * 16 + lrow) * 64 + (kk << 5) + lk8];
#pragma unroll
      for (int fr = 0; fr < 4; ++fr)
#pragma unroll
        for (int fc = 0; fc < 4; ++fc)
          acc[fr][fc] = MFMA16(af[fr], bv[fc], acc[fr][fc]);
    }
  }

  const int mlow = (lane >> 4) << 2;
#pragma unroll
  for (int fc = 0; fc < 4; ++fc) {
    int n = n0 + wc + fc * 16 + lrow;
    float bvs = bias[n];
#pragma unroll
    for (int fr = 0; fr < 4; ++fr) {
      int mb = m0 + wr + fr * 16 + mlow;
#pragma unroll
      for (int r = 0; r < 4; ++r)
        zx[(long)(mb + r) * 2048 + n] = acc[fr][fc][r] + bvs;
    }
  }
}

// ---------------------------------------------------------------------------
// LSTM step. Grid (32 jt, 4 rt-groups) x 256. Wave = one rt (16 batch rows) x
// one jt (16 hidden cols) x all 4 gates. All operand loads are coalesced 1KB
// reads of fragment-ordered L2-resident buffers.
//   hF frag (rt,ks): [l][i] = h[rt*16+(l&15)][ks*32+(l>>4)*8+i]
// ---------------------------------------------------------------------------
__global__ __launch_bounds__(256) void lstm_step2(const float* __restrict__ zx,
                                                  const __bf16* __restrict__ recF,
                                                  const __bf16* __restrict__ hFin,
                                                  __bf16* __restrict__ hFout,
                                                  float* __restrict__ cbuf,
                                                  __bf16* __restrict__ hplain,
                                                  int t, int last) {
  const int tid  = threadIdx.x;
  const int wid  = tid >> 6;
  const int lane = tid & 63;
  const int jt = blockIdx.x;
  const int rt = (blockIdx.y << 2) + wid;

  f32x4 acc[4];
#pragma unroll
  for (int g = 0; g < 4; ++g) {
    f32x4 z = {0.f, 0.f, 0.f, 0.f};
    acc[g] = z;
  }

#pragma unroll 4
  for (int ks = 0; ks < 16; ++ks) {
    bf16x8 a = *(const bf16x8*)(hFin + ((((rt << 4) + ks) << 6) + lane) * 8);
#pragma unroll
    for (int g = 0; g < 4; ++g) {
      bf16x8 b = *(const bf16x8*)(recF +
          ((((((g << 5) + jt) << 4) + ks) << 6) + lane) * 8);
      acc[g] = MFMA16(a, b, acc[g]);
    }
  }

  const int j    = (jt << 4) + (lane & 15);
  const int mlow = (lane >> 4) << 2;
  const int ks2  = j >> 5;
  const int lhi  = ((j >> 3) & 3) << 4;
  const int i2   = j & 7;

#pragma unroll
  for (int r = 0; r < 4; ++r) {
    int brow = (rt << 4) + mlow + r;
    long zb = ((long)(brow * 25 + t)) << 11;
    float zi = acc[0][r] + zx[zb + j];
    float zf = acc[1][r] + zx[zb + 512 + j];
    float zg = acc[2][r] + zx[zb + 1024 + j];
    float zo = acc[3][r] + zx[zb + 1536 + j];
    float ig = sigmf(zi);
    float fg = sigmf(zf);
    float gg = tanhf_(zg);
    float og = sigmf(zo);
    int ci = (brow << 9) + j;
    float cn = fg * cbuf[ci] + ig * gg;
    cbuf[ci] = cn;
    float hv = og * tanhf_(cn);
    hFout[((((rt << 4) + ks2) << 6) + (lhi | (brow & 15))) * 8 + i2] = (__bf16)hv;
    if (last) hplain[ci] = (__bf16)hv;
  }
}

// ---------------------------------------------------------------------------
// head: y = leaky_relu(h@w1+b1); out = softmax(y@w2+b2). One block per batch.
// ---------------------------------------------------------------------------
__global__ __launch_bounds__(128) void head_kernel(const __bf16* __restrict__ h,
                                                   const float* __restrict__ w1,
                                                   const float* __restrict__ b1,
                                                   const float* __restrict__ w2,
                                                   const float* __restrict__ b2,
                                                   float* __restrict__ out) {
  const int b = blockIdx.x;
  const int j = threadIdx.x;
  float acc = b1[j];
#pragma unroll 8
  for (int k = 0; k < 512; ++k)
    acc += (float)h[b * 512 + k] * w1[k * 128 + j];
  float y = acc > 0.f ? acc : 0.2f * acc;

  __shared__ float s0[128], s1[128];
  s0[j] = y * w2[j * 2 + 0];
  s1[j] = y * w2[j * 2 + 1];
  __syncthreads();
#pragma unroll
  for (int s = 64; s > 0; s >>= 1) {
    if (j < s) { s0[j] += s0[j + s]; s1[j] += s1[j + s]; }
    __syncthreads();
  }
  if (j == 0) {
    float l0 = s0[0] + b2[0];
    float l1 = s1[0] + b2[1];
    float m  = fmaxf(l0, l1);
    float e0 = __expf(l0 - m);
    float e1 = __expf(l1 - m);
    float inv = 1.0f / (e0 + e1);
    out[b * 2 + 0] = e0 * inv;
    out[b * 2 + 1] = e1 * inv;
  }
}

// ---------------------------------------------------------------------------
extern "C" void kernel_launch(void* const* d_in, const int* in_sizes, int n_in,
                              void* d_out, int out_size, void* d_ws, size_t ws_size,
                              hipStream_t stream) {
  const float* x    = (const float*)d_in[0];
  const float* wk   = (const float*)d_in[1];
  const float* rec  = (const float*)d_in[2];
  const float* bias = (const float*)d_in[3];
  const float* w1   = (const float*)d_in[4];
  const float* b1   = (const float*)d_in[5];
  const float* w2   = (const float*)d_in[6];
  const float* b2   = (const float*)d_in[7];
  float* out = (float*)d_out;

  char* w = (char*)d_ws;
  float*  zx     = (float*)(w + 0);              //  52,428,800
  __bf16* xb     = (__bf16*)(w + 52428800);      //  52,428,800
  __bf16* wkT    = (__bf16*)(w + 104857600);     //  16,777,216
  __bf16* recF   = (__bf16*)(w + 121634816);     //   2,097,152
  __bf16* hA     = (__bf16*)(w + 123731968);     //     262,144
  __bf16* hB     = (__bf16*)(w + 123994112);     //     262,144
  float*  cbuf   = (float*)(w + 124256256);      //     524,288
  __bf16* hplain = (__bf16*)(w + 124780544);     //     262,144
                                                 // total 125,042,688

  hipMemsetAsync(hA, 0, 262144, stream);
  hipMemsetAsync(cbuf, 0, 524288, stream);

  conv_xb  <<<12800, 256, 0, stream>>>(x, xb);
  conv_wkT <<<dim3(32, 64), 256, 0, stream>>>(wk, wkT);
  conv_recF<<<4096, 256, 0, stream>>>(rec, recF);

  gemm_bf16<<<dim3(16, 50), 256, 0, stream>>>(xb, wkT, bias, zx);

  for (int t = 0; t < 25; ++t) {
    const __bf16* hin = (t & 1) ? hB : hA;
    __bf16* hout      = (t & 1) ? hA : hB;
    lstm_step2<<<dim3(32, 4), 256, 0, stream>>>(zx, recF, hin, hout, cbuf,
                                                hplain, t, (t == 24) ? 1 : 0);
  }
  head_kernel<<<256, 128, 0, stream>>>(hplain, w1, b1, w2, b2, out);
}